// Round 5
// baseline (523.629 us; speedup 1.0000x reference)
//
#include <hip/hip_runtime.h>

using u16 = unsigned short;
typedef __bf16 bf16x8 __attribute__((ext_vector_type(8)));
typedef u16    u16x8  __attribute__((ext_vector_type(8)));
typedef u16    u16x4  __attribute__((ext_vector_type(4)));
typedef float  f32x4  __attribute__((ext_vector_type(4)));
typedef float  f32x16 __attribute__((ext_vector_type(16)));
typedef unsigned u32x4 __attribute__((ext_vector_type(4)));

#define DEV static __device__ __forceinline__

constexpr int NB = 4;          // batch
constexpr int NN = 20000;      // tokens
constexpr int DD = 64;         // model dim
constexpr int KK = 256;        // linformer K
constexpr int ROWS = NB * NN;  // 80000 flat rows
constexpr int CH = 79;         // k_proj n-chunks of 256 (78 full + 1 tail of 32)

DEV float b2f(u16 u) { union { unsigned i; float f; } c; c.i = ((unsigned)u) << 16; return c.f; }
DEV u16 f2b(float f) {
  union { float f; unsigned i; } c; c.f = f;
  unsigned i = c.i + 0x7FFFu + ((c.i >> 16) & 1u);
  return (u16)(i >> 16);
}
DEV bf16x8 ldb8(const u16* p) { return *reinterpret_cast<const bf16x8*>(p); }
DEV f32x16 mfma32(bf16x8 a, bf16x8 b, f32x16 c) { return __builtin_amdgcn_mfma_f32_32x32x16_bf16(a, b, c, 0, 0, 0); }

// ---------------------------------------------------------------------------
// Weight pre-conversion: f32 -> bf16 in MFMA B-fragment order (scaled).
// wb offsets (elems): Wq: l*4096 | Wo: 8192+l*4096 | W1: 16384+l*16384 | W2: 49152+l*16384
__global__ __launch_bounds__(256) void k_wconv(
    const float* __restrict__ Wq, const float* __restrict__ Wo,
    const float* __restrict__ W1, const float* __restrict__ W2, u16* __restrict__ wb) {
  int m = blockIdx.y, l = blockIdx.z;
  const float* src; u16* dst; int Dout, S, CT; float sc = 1.f;
  if (m == 0)      { src = Wq + l * 4096;  dst = wb + l * 4096;          Dout = 64;  S = 4;  CT = 2;
                     sc = 0.25f * 1.4426950408889634f; }  // fold SCALE*log2(e) into q
  else if (m == 1) { src = Wo + l * 4096;  dst = wb + 8192 + l * 4096;   Dout = 64;  S = 4;  CT = 2; }
  else if (m == 2) { src = W1 + l * 16384; dst = wb + 16384 + l * 16384; Dout = 256; S = 4;  CT = 8; }
  else             { src = W2 + l * 16384; dst = wb + 49152 + l * 16384; Dout = 64;  S = 16; CT = 2; }
  int slot = blockIdx.x * 256 + threadIdx.x;
  if (slot >= S * CT * 64) return;
  int s = slot / (CT * 64), rem = slot % (CT * 64);
  int ct = rem >> 6, lane = rem & 63;
  int hi = lane >> 5, lo = lane & 31;
  u16x8 o;
#pragma unroll
  for (int j = 0; j < 8; ++j) o[j] = f2b(sc * src[(s * 16 + hi * 8 + j) * Dout + ct * 32 + lo]);
  *reinterpret_cast<u16x8*>(&dst[slot * 8]) = o;
}

// ---------------------------------------------------------------------------
// projK/projV [L][N][K] f32 -> pT [L][K][N] bf16.  Full-line u16x8 stores.
__global__ __launch_bounds__(256) void k_transpose(
    const float* __restrict__ projK, const float* __restrict__ projV,
    u16* __restrict__ pKT, u16* __restrict__ pVT) {
  int nt = blockIdx.x, kt = blockIdx.y, z = blockIdx.z;
  int layer = z & 1, pv = z >> 1;
  const float* src = (pv ? projV : projK) + (size_t)layer * NN * KK;
  u16* dst = (pv ? pVT : pKT) + (size_t)layer * KK * NN;
  int n0 = nt * 64, k0 = kt * 64;
  __shared__ float lds[64][65];  // lds[k][n]
  int t = threadIdx.x;
  int r = t >> 4, c4 = (t & 15) * 4;
#pragma unroll
  for (int i = 0; i < 4; ++i) {
    int rr = r + i * 16;
    float4 v = make_float4(0.f, 0.f, 0.f, 0.f);
    if (n0 + rr < NN) v = *reinterpret_cast<const float4*>(&src[(size_t)(n0 + rr) * KK + k0 + c4]);
    lds[c4 + 0][rr] = v.x; lds[c4 + 1][rr] = v.y; lds[c4 + 2][rr] = v.z; lds[c4 + 3][rr] = v.w;
  }
  __syncthreads();
  int kr = t >> 3, nb = (t & 7) * 8;
#pragma unroll
  for (int p = 0; p < 2; ++p) {
    int k = kr + p * 32;
    if (n0 + nb < NN) {  // NN%64==32 -> 8-chunks are all-or-nothing
      u16x8 o;
#pragma unroll
      for (int j = 0; j < 8; ++j) o[j] = f2b(lds[k][nb + j]);
      *reinterpret_cast<u16x8*>(&dst[(size_t)(k0 + k) * NN + n0 + nb]) = o;
    }
  }
}

// ---------------------------------------------------------------------------
// x [b][n][64] bf16 -> xT [b][64][NN] bf16, full-line u16x8 stores.
__global__ __launch_bounds__(256) void k_xt(const u16* __restrict__ x, u16* __restrict__ xT) {
  int nt = blockIdx.x, b = blockIdx.y;
  int n0 = nt * 64;
  __shared__ u16 lds[64][70];
  int t = threadIdx.x;
  int r = t >> 4, c4 = (t & 15) * 4;
  const u16* xb = x + (size_t)b * NN * 64;
#pragma unroll
  for (int i = 0; i < 4; ++i) {
    int rr = r + i * 16;
    u16x4 v = {};
    if (n0 + rr < NN) v = *reinterpret_cast<const u16x4*>(&xb[(size_t)(n0 + rr) * 64 + c4]);
    lds[c4 + 0][rr] = v[0]; lds[c4 + 1][rr] = v[1];
    lds[c4 + 2][rr] = v[2]; lds[c4 + 3][rr] = v[3];
  }
  __syncthreads();
  int dr = t >> 3, nb = (t & 7) * 8;
  u16* xo = xT + (size_t)b * 64 * NN;
#pragma unroll
  for (int p = 0; p < 2; ++p) {
    int d = dr + p * 32;
    if (n0 + nb < NN) {
      u16x8 o;
#pragma unroll
      for (int j = 0; j < 8; ++j) o[j] = lds[d][nb + j];
      *reinterpret_cast<u16x8*>(&xo[(size_t)d * NN + n0 + nb]) = o;
    }
  }
}

// ---------------------------------------------------------------------------
// x[b,n,d] = emb[n,d] * expr[b,n] -> bf16.  8 elems/thread, grid 2500.
__global__ __launch_bounds__(256) void k_embed(
    const float* __restrict__ expr, const float* __restrict__ emb, u16* __restrict__ xb) {
  int idx8 = (blockIdx.x * 256 + threadIdx.x) * 8;
  int b = idx8 / (NN * DD);
  int rem = idx8 - b * (NN * DD);
  int n = rem >> 6, d = rem & 63;
  float4 e0 = *reinterpret_cast<const float4*>(&emb[(n << 6) + d]);
  float4 e1 = *reinterpret_cast<const float4*>(&emb[(n << 6) + d + 4]);
  float s = expr[b * NN + n];
  u16x8 o;
  o[0] = f2b(e0.x * s); o[1] = f2b(e0.y * s); o[2] = f2b(e0.z * s); o[3] = f2b(e0.w * s);
  o[4] = f2b(e1.x * s); o[5] = f2b(e1.y * s); o[6] = f2b(e1.z * s); o[7] = f2b(e1.w * s);
  *reinterpret_cast<u16x8*>(&xb[idx8]) = o;
}

// ---------------------------------------------------------------------------
// Row GEMM  out[M,64] = A[M,64] @ W[64,64]  (+ bias + residual + LayerNorm)
template <int EPI>
__global__ __launch_bounds__(256) void k_gemm_64_64(
    const u16* __restrict__ A, const u16* __restrict__ WB,
    const float* __restrict__ bias, const u16* __restrict__ res,
    const float* __restrict__ g, const float* __restrict__ be, u16* __restrict__ out) {
  int t = threadIdx.x, w = t >> 6, lane = t & 63;
  int lo = lane & 31, hi = lane >> 5;
  int unit = blockIdx.x * 4 + w;
  if (unit >= ROWS / 64) return;
  bf16x8 wf[4][2];
#pragma unroll
  for (int s = 0; s < 4; ++s)
#pragma unroll
    for (int ct = 0; ct < 2; ++ct) wf[s][ct] = ldb8(&WB[((s * 2 + ct) * 64 + lane) * 8]);
  float bia[2], gg[2], bb[2];
  if (EPI) {
#pragma unroll
    for (int ct = 0; ct < 2; ++ct) {
      bia[ct] = bias[ct * 32 + lo];
      gg[ct] = g[ct * 32 + lo];
      bb[ct] = be[ct * 32 + lo];
    }
  }
  f32x16 acc[2][2] = {};
  int r0 = unit * 64;
#pragma unroll
  for (int s = 0; s < 4; ++s) {
#pragma unroll
    for (int rt = 0; rt < 2; ++rt) {
      bf16x8 a = ldb8(&A[(size_t)(r0 + rt * 32 + lo) * 64 + s * 16 + hi * 8]);
      acc[rt][0] = mfma32(a, wf[s][0], acc[rt][0]);
      acc[rt][1] = mfma32(a, wf[s][1], acc[rt][1]);
    }
  }
#pragma unroll
  for (int rt = 0; rt < 2; ++rt) {
#pragma unroll
    for (int reg = 0; reg < 16; ++reg) {
      int row = r0 + rt * 32 + (reg & 3) + 8 * (reg >> 2) + 4 * hi;
      if (EPI == 0) {
        out[(size_t)row * 64 + lo] = f2b(acc[rt][0][reg]);
        out[(size_t)row * 64 + 32 + lo] = f2b(acc[rt][1][reg]);
      } else {
        float a0 = acc[rt][0][reg] + bia[0] + b2f(res[(size_t)row * 64 + lo]);
        float a1 = acc[rt][1][reg] + bia[1] + b2f(res[(size_t)row * 64 + 32 + lo]);
        float su = a0 + a1, sq = a0 * a0 + a1 * a1;
#pragma unroll
        for (int m = 1; m <= 16; m <<= 1) { su += __shfl_xor(su, m); sq += __shfl_xor(sq, m); }
        float mean = su * (1.f / 64.f);
        float var = sq * (1.f / 64.f) - mean * mean;
        float rstd = rsqrtf(var + 1e-5f);
        out[(size_t)row * 64 + lo] = f2b((a0 - mean) * rstd * gg[0] + bb[0]);
        out[(size_t)row * 64 + 32 + lo] = f2b((a1 - mean) * rstd * gg[1] + bb[1]);
      }
    }
  }
}

// ---------------------------------------------------------------------------
// FFN1: out[M,256] = gelu(A[M,64] @ W1[64,256] + bias)
__global__ __launch_bounds__(256, 2) void k_gemm_64_256(
    const u16* __restrict__ A, const u16* __restrict__ WB,
    const float* __restrict__ bias, u16* __restrict__ out) {
  int t = threadIdx.x, w = t >> 6, lane = t & 63;
  int lo = lane & 31, hi = lane >> 5;
  int colg = w & 1;
  int unit = blockIdx.x * 2 + (w >> 1);
  if (unit >= ROWS / 32) return;
  bf16x8 wf[4][4];
  float bia[4];
#pragma unroll
  for (int s = 0; s < 4; ++s)
#pragma unroll
    for (int ct = 0; ct < 4; ++ct) wf[s][ct] = ldb8(&WB[((s * 8 + colg * 4 + ct) * 64 + lane) * 8]);
#pragma unroll
  for (int ct = 0; ct < 4; ++ct) bia[ct] = bias[colg * 128 + ct * 32 + lo];
  f32x16 acc[4] = {};
  int r0 = unit * 32;
#pragma unroll
  for (int s = 0; s < 4; ++s) {
    bf16x8 a = ldb8(&A[(size_t)(r0 + lo) * 64 + s * 16 + hi * 8]);
#pragma unroll
    for (int ct = 0; ct < 4; ++ct) acc[ct] = mfma32(a, wf[s][ct], acc[ct]);
  }
#pragma unroll
  for (int ct = 0; ct < 4; ++ct) {
#pragma unroll
    for (int reg = 0; reg < 16; ++reg) {
      int row = r0 + (reg & 3) + 8 * (reg >> 2) + 4 * hi;
      float x = acc[ct][reg] + bia[ct];
      float gel = 0.5f * x * (1.f + erff(x * 0.7071067811865475f));
      out[(size_t)row * 256 + colg * 128 + ct * 32 + lo] = f2b(gel);
    }
  }
}

// ---------------------------------------------------------------------------
// FFN2: LN(A[M,256] @ W2[256,64] + bias + res)
__global__ __launch_bounds__(256) void k_gemm_256_64(
    const u16* __restrict__ A, const u16* __restrict__ WB,
    const float* __restrict__ bias, const u16* __restrict__ res,
    const float* __restrict__ g, const float* __restrict__ be,
    u16* __restrict__ outb, float* __restrict__ outf) {
  int t = threadIdx.x, w = t >> 6, lane = t & 63;
  int lo = lane & 31, hi = lane >> 5;
  int unit = blockIdx.x * 4 + w;
  if (unit >= ROWS / 64) return;
  float bia[2], gg[2], bb[2];
#pragma unroll
  for (int ct = 0; ct < 2; ++ct) {
    bia[ct] = bias[ct * 32 + lo];
    gg[ct] = g[ct * 32 + lo];
    bb[ct] = be[ct * 32 + lo];
  }
  f32x16 acc[2][2] = {};
  int r0 = unit * 64;
#pragma unroll
  for (int s = 0; s < 16; ++s) {
    bf16x8 w0 = ldb8(&WB[((s * 2 + 0) * 64 + lane) * 8]);
    bf16x8 w1 = ldb8(&WB[((s * 2 + 1) * 64 + lane) * 8]);
#pragma unroll
    for (int rt = 0; rt < 2; ++rt) {
      bf16x8 a = ldb8(&A[(size_t)(r0 + rt * 32 + lo) * 256 + s * 16 + hi * 8]);
      acc[rt][0] = mfma32(a, w0, acc[rt][0]);
      acc[rt][1] = mfma32(a, w1, acc[rt][1]);
    }
  }
#pragma unroll
  for (int rt = 0; rt < 2; ++rt) {
#pragma unroll
    for (int reg = 0; reg < 16; ++reg) {
      int row = r0 + rt * 32 + (reg & 3) + 8 * (reg >> 2) + 4 * hi;
      float a0 = acc[rt][0][reg] + bia[0] + b2f(res[(size_t)row * 64 + lo]);
      float a1 = acc[rt][1][reg] + bia[1] + b2f(res[(size_t)row * 64 + 32 + lo]);
      float su = a0 + a1, sq = a0 * a0 + a1 * a1;
#pragma unroll
      for (int m = 1; m <= 16; m <<= 1) { su += __shfl_xor(su, m); sq += __shfl_xor(sq, m); }
      float mean = su * (1.f / 64.f);
      float var = sq * (1.f / 64.f) - mean * mean;
      float rstd = rsqrtf(var + 1e-5f);
      float o0 = (a0 - mean) * rstd * gg[0] + bb[0];
      float o1 = (a1 - mean) * rstd * gg[1] + bb[1];
      if (outb) {
        outb[(size_t)row * 64 + lo] = f2b(o0);
        outb[(size_t)row * 64 + 32 + lo] = f2b(o1);
      }
      if (outf) {
        outf[(size_t)row * 64 + lo] = o0;
        outf[(size_t)row * 64 + 32 + lo] = o1;
      }
    }
  }
}

// ---------------------------------------------------------------------------
// Linformer projection partials: part[proj][b][c][64 d][256 k] = sum_n xT[d][n]*pT[k][n]
// grid (CH=79 chunks of 256 n, NB, 2 proj), 4 waves: (d-half, k-half).
// Main path fully unrolled (16 steps, imm-offset loads) for deep vmcnt pipelining.
__global__ __launch_bounds__(256, 3) void k_proj(
    const u16* __restrict__ xT, const u16* __restrict__ pKT_l, const u16* __restrict__ pVT_l,
    float* __restrict__ part) {
  int c = blockIdx.x, b = blockIdx.y, proj = blockIdx.z;
  const u16* P = proj ? pVT_l : pKT_l;
  int t = threadIdx.x, w = t >> 6, lane = t & 63;
  int lo = lane & 31, hi = lane >> 5;
  int d0 = (w & 1) * 32;
  int kbase = (w >> 1) * 128;
  int n0 = c * 256;
  const u16* xr = xT + ((size_t)b * 64 + d0 + lo) * NN + n0 + hi * 8;
  const u16* pr0 = P + (size_t)(kbase + lo) * NN + n0 + hi * 8;
  const u16* pr1 = pr0 + (size_t)32 * NN;
  const u16* pr2 = pr0 + (size_t)64 * NN;
  const u16* pr3 = pr0 + (size_t)96 * NN;
  f32x16 acc[4] = {};
  if (n0 + 256 <= NN) {
#pragma unroll
    for (int s = 0; s < 16; ++s) {
      int nb = s * 16;
      bf16x8 a = ldb8(&xr[nb]);
      acc[0] = mfma32(a, ldb8(&pr0[nb]), acc[0]);
      acc[1] = mfma32(a, ldb8(&pr1[nb]), acc[1]);
      acc[2] = mfma32(a, ldb8(&pr2[nb]), acc[2]);
      acc[3] = mfma32(a, ldb8(&pr3[nb]), acc[3]);
    }
  } else {
    int steps = (NN - n0) >> 4;  // tail chunk (32 n -> 2 steps)
    for (int s = 0; s < steps; ++s) {
      int nb = s * 16;
      bf16x8 a = ldb8(&xr[nb]);
      acc[0] = mfma32(a, ldb8(&pr0[nb]), acc[0]);
      acc[1] = mfma32(a, ldb8(&pr1[nb]), acc[1]);
      acc[2] = mfma32(a, ldb8(&pr2[nb]), acc[2]);
      acc[3] = mfma32(a, ldb8(&pr3[nb]), acc[3]);
    }
  }
  float* dst = part + ((size_t)(proj * NB + b) * CH + c) * (64 * 256);
#pragma unroll
  for (int gI = 0; gI < 4; ++gI)
#pragma unroll
    for (int r = 0; r < 16; ++r) {
      int d = d0 + (r & 3) + 8 * (r >> 2) + 4 * hi;
      dst[d * 256 + kbase + gI * 32 + lo] = acc[gI][r];
    }
}

// ---------------------------------------------------------------------------
// Reduce CH chunk-partials + apply Wk/Wv.  grid (32 kslices of 8, NB, 2).
// proj0 -> kbuf [b][256][64] with rows PERMUTED (bits 2<->3 of key index) so that
// k_attn's S^T C-layout equals the PV B-operand layout with no cross-lane moves.
// proj1 -> vT [b][64][256] unpermuted.
__global__ __launch_bounds__(256) void k_p2(
    const float* __restrict__ part, const float* __restrict__ Wk_l, const float* __restrict__ Wv_l,
    u16* __restrict__ kbuf, u16* __restrict__ vT) {
  int ks = blockIdx.x, b = blockIdx.y, proj = blockIdx.z;
  int k0 = ks * 8;
  const float* W = proj ? Wv_l : Wk_l;
  __shared__ float low[64][8];
  int t = threadIdx.x;
  const float* src = part + (size_t)(proj * NB + b) * CH * (64 * 256);
#pragma unroll
  for (int i = 0; i < 2; ++i) {
    int idx = i * 256 + t;
    int e = idx >> 3, k = idx & 7;
    float s = 0.f;
    for (int cc = 0; cc < CH; ++cc) s += src[(size_t)cc * (64 * 256) + e * 256 + k0 + k];
    low[e][k] = s;
  }
  __syncthreads();
#pragma unroll
  for (int i = 0; i < 2; ++i) {
    int idx = i * 256 + t;
    int d = idx & 63, kk = idx >> 6;
    float a = 0.f;
#pragma unroll
    for (int e = 0; e < 64; ++e) a += low[e][kk] * W[e * 64 + d];
    u16 o = f2b(a);
    if (proj == 0) {
      int key = k0 + kk;
      int row = (key & ~12) | ((key & 4) << 1) | ((key & 8) >> 1);  // involution
      kbuf[((size_t)b * KK + row) * 64 + d] = o;
    } else {
      vT[((size_t)b * 64 + d) * KK + k0 + kk] = o;
    }
  }
}

// ---------------------------------------------------------------------------
// Fused Linformer attention, register-only, shuffle-free main loop.
// kbuf rows are permuted (k_p2) so S^T C-regs ARE the PV B-fragment: bu0=s[0..7], bu1=s[8..15].
// q pre-scaled by SCALE*log2(e) (k_wconv).  grid (157, 4 heads, NB).
__global__ __launch_bounds__(256) void k_attn(
    const u16* __restrict__ q, const u16* __restrict__ kbuf, const u16* __restrict__ vT,
    u16* __restrict__ ao) {
  int t = threadIdx.x, w = t >> 6, lane = t & 63;
  int lo = lane & 31, hi = lane >> 5;
  int h = blockIdx.y, b = blockIdx.z;
  int n0w = blockIdx.x * 128 + w * 32;
  if (n0w >= NN) return;
  const u16* qb = q + (size_t)b * NN * 64;
  const u16* kb = kbuf + (size_t)b * KK * 64 + h * 16;
  const u16* vtb = vT + (size_t)b * 64 * KK + (size_t)(h * 16 + (lane & 15)) * KK;
  u16* aob = ao + (size_t)b * NN * 64;
  bf16x8 qf = ldb8(&qb[(size_t)(n0w + lo) * 64 + h * 16 + hi * 8]);
  f32x16 acc = {};
  float ssum = 0.f;
#pragma unroll
  for (int kt = 0; kt < 8; ++kt) {
    bf16x8 kf = ldb8(&kb[(size_t)(kt * 32 + lo) * 64 + hi * 8]);
    f32x16 z = {};
    f32x16 s = mfma32(kf, qf, z);  // S^T tile (permuted key rows)
#pragma unroll
    for (int r = 0; r < 16; ++r) { s[r] = exp2f(s[r]); ssum += s[r]; }
#pragma unroll
    for (int c = 0; c < 2; ++c) {
      u32x4 d;
#pragma unroll
      for (int i = 0; i < 4; ++i) {
        unsigned a0 = __builtin_bit_cast(unsigned, s[c * 8 + 2 * i]) + 0x8000u;
        unsigned a1 = __builtin_bit_cast(unsigned, s[c * 8 + 2 * i + 1]) + 0x8000u;
        d[i] = __builtin_amdgcn_perm(a1, a0, 0x07060302u);  // pack hi16s (round-half-up)
      }
      bf16x8 af = ldb8(&vtb[kt * 32 + c * 16 + hi * 8]);
      acc = mfma32(af, __builtin_bit_cast(bf16x8, d), acc);
    }
  }
  ssum += __shfl_xor(ssum, 32);
  float inv = 1.f / ssum;
  float o[8], ox[8];
#pragma unroll
  for (int r = 0; r < 8; ++r) o[r] = acc[r] * inv;  // d rows 0..15 live in regs 0..7
#pragma unroll
  for (int r = 0; r < 8; ++r) ox[r] = __shfl_xor(o[r], 32);
  u16x8 st;
#pragma unroll
  for (int j = 0; j < 4; ++j) {
    st[j] = f2b(hi ? ox[4 + j] : o[j]);
    st[4 + j] = f2b(hi ? o[4 + j] : ox[j]);
  }
  *reinterpret_cast<u16x8*>(&aob[(size_t)(n0w + lo) * 64 + h * 16 + hi * 8]) = st;
}

// ---------------------------------------------------------------------------
extern "C" void kernel_launch(void* const* d_in, const int* in_sizes, int n_in,
                              void* d_out, int out_size, void* d_ws, size_t ws_size,
                              hipStream_t stream) {
  const float* expr = (const float*)d_in[0];
  const float* emb  = (const float*)d_in[1];
  const float* Wq   = (const float*)d_in[2];
  const float* Wk   = (const float*)d_in[3];
  const float* Wv   = (const float*)d_in[4];
  const float* projK = (const float*)d_in[5];
  const float* projV = (const float*)d_in[6];
  const float* Wo   = (const float*)d_in[7];
  const float* bo   = (const float*)d_in[8];
  const float* g1   = (const float*)d_in[9];
  const float* be1  = (const float*)d_in[10];
  const float* W1   = (const float*)d_in[11];
  const float* bf1  = (const float*)d_in[12];
  const float* W2   = (const float*)d_in[13];
  const float* bf2  = (const float*)d_in[14];
  const float* g2   = (const float*)d_in[15];
  const float* be2  = (const float*)d_in[16];
  float* out = (float*)d_out;
  char* ws = (char*)d_ws;

  // workspace layout (bytes); ws_size ~268 MB (fillBufferAligned WRITE_SIZE = 256 MiB)
  u16* xb0 = (u16*)(ws + 0);                 // 10,240,000
  u16* xb1 = (u16*)(ws + 10240000);          // 10,240,000
  u16* xb2 = (u16*)(ws + 20480000);          // 10,240,000
  u16* qb  = (u16*)(ws + 30720000);          // 10,240,000
  u16* aob = (u16*)(ws + 40960000);          // 10,240,000
  u16* hb  = (u16*)(ws + 51200000);          // 40,960,000  (FFN hidden)
  u16* pKT = (u16*)(ws + 92160000);          // 20,480,000 (2 layers)
  u16* pVT = (u16*)(ws + 112640000);         // 20,480,000
  u16* xTb = (u16*)(ws + 133120000);         // 10,240,000
  u16* kB  = (u16*)(ws + 143360000);         // 131,072
  u16* vTB = (u16*)(ws + 143491072);         // 131,072
  u16* wb  = (u16*)(ws + 143622144);         // 163,840
  float* part = (float*)(ws + 143786240);    // 41,418,752 (8*79*64*256*4) end ~185.2 MB

  k_wconv<<<dim3(8, 4, 2), 256, 0, stream>>>(Wq, Wo, W1, W2, wb);
  k_transpose<<<dim3(313, 4, 4), 256, 0, stream>>>(projK, projV, pKT, pVT);
  k_embed<<<2500, 256, 0, stream>>>(expr, emb, xb0);

  const u16* xin = xb0;
  for (int l = 0; l < 2; ++l) {
    const u16* wbq = wb + l * 4096;
    const u16* wbo = wb + 8192 + l * 4096;
    const u16* wb1 = wb + 16384 + l * 16384;
    const u16* wb2 = wb + 49152 + l * 16384;
    k_gemm_64_64<0><<<313, 256, 0, stream>>>(xin, wbq, nullptr, nullptr, nullptr, nullptr, qb);
    k_xt<<<dim3(313, NB), 256, 0, stream>>>(xin, xTb);
    k_proj<<<dim3(CH, NB, 2), 256, 0, stream>>>(xTb, pKT + (size_t)l * KK * NN, pVT + (size_t)l * KK * NN, part);
    k_p2<<<dim3(32, NB, 2), 256, 0, stream>>>(part, Wk + l * 4096, Wv + l * 4096, kB, vTB);
    k_attn<<<dim3(157, 4, NB), 256, 0, stream>>>(qb, kB, vTB, aob);
    k_gemm_64_64<1><<<313, 256, 0, stream>>>(aob, wbo, bo + l * 64, xin, g1 + l * 64, be1 + l * 64, xb1);
    k_gemm_64_256<<<1250, 256, 0, stream>>>(xb1, wb1, bf1 + l * 256, hb);
    k_gemm_256_64<<<313, 256, 0, stream>>>(hb, wb2, bf2 + l * 64, xb1,
                                           g2 + l * 64, be2 + l * 64,
                                           l == 0 ? xb2 : nullptr, l == 1 ? out : nullptr);
    xin = xb2;
  }
}